// Round 17
// baseline (408.425 us; speedup 1.0000x reference)
//
#include <hip/hip_runtime.h>
#include <hip/hip_fp16.h>

#define N_NODES 100000
#define N_EDGES 1600000
#define FEAT 32

#define BUCKET_SHIFT 7                       // 128 nodes per bucket
#define NBKT 782                             // ceil(100000/128)
#define P1_BLOCKS 800
#define EPB (N_EDGES / P1_BLOCKS)            // 2000 edges per pass-1 block
#define EPB2 (EPB / 2)                       // 1000 edge-pairs
#define SCAN_N (NBKT * P1_BLOCKS)            // 625600
#define STAGE_CAP 4096                       // LDS record cap (16KB); avg 2046/bucket

// ---------------- CSR build: 2-pass LDS-binned counting sort ----------------

__global__ __launch_bounds__(256) void bin_count(const int* __restrict__ col,
                                                 int* __restrict__ hist) {
    __shared__ int h[NBKT];
    int t = threadIdx.x;
    for (int i = t; i < NBKT; i += 256) h[i] = 0;
    __syncthreads();
    const int2* col2 = (const int2*)(col + blockIdx.x * EPB);
    for (int i = t; i < EPB2; i += 256) {
        int2 c = col2[i];
        atomicAdd(&h[c.x >> BUCKET_SHIFT], 1);
        atomicAdd(&h[c.y >> BUCKET_SHIFT], 1);
    }
    __syncthreads();
    for (int i = t; i < NBKT; i += 256)
        hist[i * P1_BLOCKS + blockIdx.x] = h[i];     // bucket-major
}

__global__ __launch_bounds__(1024) void scan_block(const int* __restrict__ cnt,
                                                   int* __restrict__ ex,
                                                   int* __restrict__ bsum, int n) {
    __shared__ int s[1024];
    int t = threadIdx.x;
    int i = blockIdx.x * 1024 + t;
    int v = (i < n) ? cnt[i] : 0;
    s[t] = v;
    __syncthreads();
    #pragma unroll
    for (int off = 1; off < 1024; off <<= 1) {
        int x = (t >= off) ? s[t - off] : 0;
        __syncthreads();
        s[t] += x;
        __syncthreads();
    }
    if (i < n) ex[i + 1] = s[t];
    if (t == 1023) bsum[blockIdx.x] = s[1023];
}

__global__ __launch_bounds__(1024) void scan_sums(int* __restrict__ bsum, int nb) {
    __shared__ int s[1024];
    int t = threadIdx.x;
    int v = (t < nb) ? bsum[t] : 0;
    s[t] = v;
    __syncthreads();
    #pragma unroll
    for (int off = 1; off < 1024; off <<= 1) {
        int x = (t >= off) ? s[t - off] : 0;
        __syncthreads();
        s[t] += x;
        __syncthreads();
    }
    if (t < nb) bsum[t] = s[t] - v;       // exclusive
}

__global__ __launch_bounds__(1024) void scan_add(int* __restrict__ ex,
                                                 const int* __restrict__ bsum, int n) {
    int i = blockIdx.x * 1024 + threadIdx.x;
    if (i < n) ex[i + 1] += bsum[blockIdx.x];
    if (blockIdx.x == 0 && threadIdx.x == 0) ex[0] = 0;
}

__global__ __launch_bounds__(256) void bin_scatter(const int* __restrict__ row,
                                                   const int* __restrict__ col,
                                                   const int* __restrict__ hoff,
                                                   int* __restrict__ binned) {
    __shared__ int cur[NBKT];
    int t = threadIdx.x;
    for (int i = t; i < NBKT; i += 256) cur[i] = hoff[i * P1_BLOCKS + blockIdx.x];
    __syncthreads();
    const int2* col2 = (const int2*)(col + blockIdx.x * EPB);
    const int2* row2 = (const int2*)(row + blockIdx.x * EPB);
    for (int i = t; i < EPB2; i += 256) {
        int2 c = col2[i];
        int2 r = row2[i];
        int p0 = atomicAdd(&cur[c.x >> BUCKET_SHIFT], 1);
        binned[p0] = ((c.x & 127) << 17) | r.x;      // r < 2^17
        int p1 = atomicAdd(&cur[c.y >> BUCKET_SHIFT], 1);
        binned[p1] = ((c.y & 127) << 17) | r.y;
    }
}

// One block per bucket (782 blocks); records staged in LDS (single global read).
// h[] padded to 256 (entries >=128 stay zero through the scan; unused).
__global__ __launch_bounds__(256) void bucket_sort(const int* __restrict__ binned,
                                                   const int* __restrict__ hoff,
                                                   int* __restrict__ rp,
                                                   int* __restrict__ csrc) {
    __shared__ int h[256];
    __shared__ int rec[STAGE_CAP];
    int b = blockIdx.x, t = threadIdx.x;
    int bstart = hoff[b * P1_BLOCKS];
    int bend   = hoff[(b + 1) * P1_BLOCKS];
    int nrec = bend - bstart;
    bool staged = (nrec <= STAGE_CAP);

    h[t] = 0;
    __syncthreads();
    if (staged) {
        for (int i = t; i < nrec; i += 256) {
            int v = binned[bstart + i];
            rec[i] = v;
            atomicAdd(&h[v >> 17], 1);
        }
    } else {
        for (int p = bstart + t; p < bend; p += 256)
            atomicAdd(&h[binned[p] >> 17], 1);
    }
    __syncthreads();
    int deg = h[t];
    #pragma unroll
    for (int off = 1; off < 256; off <<= 1) {       // inclusive scan
        int x = (t >= off) ? h[t - off] : 0;
        __syncthreads();
        h[t] += x;
        __syncthreads();
    }
    int mystart = bstart + h[t] - deg;
    int node = (b << BUCKET_SHIFT) + t;
    if (t < 128 && node < N_NODES) rp[node] = mystart;
    if (b == NBKT - 1 && t == 0) rp[N_NODES] = N_EDGES;
    __syncthreads();
    h[t] = mystart;                                  // cursor (t<128 meaningful)
    __syncthreads();
    if (staged) {
        for (int i = t; i < nrec; i += 256) {
            int v = rec[i];
            int pos = atomicAdd(&h[v >> 17], 1);
            csrc[pos] = v & 0x1FFFF;
        }
    } else {
        for (int p = bstart + t; p < bend; p += 256) {
            int v = binned[p];
            int pos = atomicAdd(&h[v >> 17], 1);
            csrc[pos] = v & 0x1FFFF;
        }
    }
}

// ---------------- layer kernels (R12-proven, fp16 messages) ----------------

// m[n][f] = relu(b[f] + sum_k x[n][k] * W[k][f]) from fp32 x, fp16 out.
__global__ __launch_bounds__(256) void node_msg0(const float* __restrict__ h,
                                                 const float* __restrict__ W,
                                                 const float* __restrict__ b,
                                                 __half* __restrict__ m) {
    __shared__ float WsT[32 * 33];                  // stride 33: conflict-free
    __shared__ float bs[32];
    int t = threadIdx.x;
    for (int i = t; i < 1024; i += 256) {
        int k = i >> 5, f = i & 31;
        WsT[f * 33 + k] = W[i];
    }
    if (t < 32) bs[t] = b[t];
    __syncthreads();

    int node = blockIdx.x * 8 + (t >> 5);           // grid exact: no tail
    int f = t & 31;
    const float4* hp = (const float4*)(h + node * 32);
    const float* wr = &WsT[f * 33];
    float acc = bs[f];
    #pragma unroll
    for (int i = 0; i < 8; i++) {
        float4 q = hp[i];
        acc = fmaf(q.x, wr[4 * i + 0], acc);
        acc = fmaf(q.y, wr[4 * i + 1], acc);
        acc = fmaf(q.z, wr[4 * i + 2], acc);
        acc = fmaf(q.w, wr[4 * i + 3], acc);
    }
    m[node * 32 + f] = __float2half(fmaxf(acc, 0.f));
}

// Fused layer: gather-mean of fp16 m + output matvec -> h_new (+resid), then
// the NEXT layer's message matvec on in-register h_new -> m_out.
// 12 params: x, hin, m, rp, csrc, W1, b1, W2, b2, hout, mout, coords.
template <int OUT, bool XIN, bool RESID, bool MSG>
__global__ __launch_bounds__(256) void fused_layer(
    const float* __restrict__ x,        // 1  fp32 node input (XIN)
    const __half* __restrict__ hin,     // 2  fp16 node input (!XIN); may alias hout
    const __half* __restrict__ m,       // 3  messages of this layer
    const int* __restrict__ rp,         // 4
    const int* __restrict__ csrc,       // 5
    const float* __restrict__ W1,       // 6  [64, OUT] output MLP
    const float* __restrict__ b1,       // 7  [OUT]
    const float* __restrict__ W2,       // 8  [32, 32] next msg MLP (MSG)
    const float* __restrict__ b2,       // 9  [32]
    __half* __restrict__ hout,          // 10 fp16 h_new (OUT==32)
    __half* __restrict__ mout,          // 11 fp16 m_next (MSG)
    float* __restrict__ coords)         // 12 fp32 final out (OUT==2)
{
    __shared__ float Ws1[64 * OUT];
    __shared__ float bs1[OUT];
    __shared__ float Ws2[MSG ? 1024 : 1];
    __shared__ float bs2[MSG ? 32 : 1];
    int t = threadIdx.x;
    for (int i = t; i < 64 * OUT; i += 256) Ws1[i] = W1[i];
    if (t < OUT) bs1[t] = b1[t];
    if (MSG) {
        for (int i = t; i < 1024; i += 256) Ws2[i] = W2[i];
        if (t < 32) bs2[t] = b2[t];
    }
    __syncthreads();

    int node = blockIdx.x * 8 + (t >> 5);           // grid exact: no tail
    int f = t & 31;

    int start = rp[node];
    int end   = rp[node + 1];
    int deg   = end - start;

    float a0 = 0.f, a1 = 0.f, a2 = 0.f, a3 = 0.f;
    int p = start;
    while (p < end) {
        int nrem = end - p;
        int cnt = (nrem < 32) ? nrem : 32;
        int src_f = (f < cnt) ? csrc[p + f] : 0;   // one coalesced load / chunk
        int k = 0;
        for (; k + 4 <= cnt; k += 4) {
            int s0 = __shfl(src_f, k,     32);
            int s1 = __shfl(src_f, k + 1, 32);
            int s2 = __shfl(src_f, k + 2, 32);
            int s3 = __shfl(src_f, k + 3, 32);
            a0 += __half2float(m[s0 * 32 + f]);
            a1 += __half2float(m[s1 * 32 + f]);
            a2 += __half2float(m[s2 * 32 + f]);
            a3 += __half2float(m[s3 * 32 + f]);
        }
        for (; k < cnt; k++) {
            int s = __shfl(src_f, k, 32);
            a0 += __half2float(m[s * 32 + f]);
        }
        p += cnt;
    }
    float agg = (a0 + a1) + (a2 + a3);
    agg = (deg > 0) ? agg / (float)deg : 0.f;

    float hf = XIN ? x[node * 32 + f] : __half2float(hin[node * 32 + f]);

    float acc = (f < OUT) ? bs1[f] : 0.f;
    #pragma unroll
    for (int k = 0; k < 32; k++) {
        float hk = __shfl(hf, k, 32);
        float ak = __shfl(agg, k, 32);
        if (f < OUT) {
            acc = fmaf(hk, Ws1[k * OUT + f], acc);
            acc = fmaf(ak, Ws1[(32 + k) * OUT + f], acc);
        }
    }

    if (OUT == 2) {
        if (f < 2) coords[node * 2 + f] = acc;
        return;
    }

    float hnew = fmaxf(acc, 0.f);
    if (RESID) hnew += hf;
    hout[node * 32 + f] = __float2half(hnew);       // own element only: in-place safe

    if (MSG) {
        float acc2 = bs2[f];
        #pragma unroll
        for (int k = 0; k < 32; k++) {
            float hk = __shfl(hnew, k, 32);
            acc2 = fmaf(hk, Ws2[k * 32 + f], acc2);
        }
        mout[node * 32 + f] = __float2half(fmaxf(acc2, 0.f));
    }
}

// ---------------- launch ----------------

extern "C" void kernel_launch(void* const* d_in, const int* in_sizes, int n_in,
                              void* d_out, int out_size, void* d_ws, size_t ws_size,
                              hipStream_t stream) {
    const float* x      = (const float*)d_in[0];
    const int*   ei     = (const int*)d_in[1];     // [2, E]: row then col
    const float* msg_w  = (const float*)d_in[3];   // [4,32,32]
    const float* msg_b  = (const float*)d_in[4];   // [4,32]
    const float* out_w  = (const float*)d_in[5];   // [3,64,32]
    const float* out_b  = (const float*)d_in[6];   // [3,32]
    const float* last_w = (const float*)d_in[7];   // [64,2]
    const float* last_b = (const float*)d_in[8];   // [2]
    float* coords = (float*)d_out;

    const int* row = ei;
    const int* col = ei + N_EDGES;

    // workspace carve-up (~34 MB); binned overlaps hA (dead before first fused)
    __half* hA = (__half*)d_ws;                     // 6.4 MB
    __half* mA = hA + N_NODES * FEAT;               // 6.4 MB
    __half* mB = mA + N_NODES * FEAT;               // 6.4 MB
    int* rp    = (int*)(mB + N_NODES * FEAT);       // [N+1]
    int* hoff  = rp + (N_NODES + 1);                // [SCAN_N+1] 2.5 MB
    int* bsum  = hoff + (SCAN_N + 1);               // [1024]
    int* hist  = bsum + 1024;                       // [SCAN_N] 2.5 MB
    int* csrc  = hist + SCAN_N;                     // [E] 6.4 MB
    int* binned = (int*)hA;                         // [E] 6.4 MB (overlap hA+mA)

    const int SCAN_BLOCKS = (SCAN_N + 1023) / 1024;    // 611
    const int NODE_BLOCKS = N_NODES / 8;               // 12500 exact

    // --- build CSR (by destination), no global atomics ---
    bin_count<<<P1_BLOCKS, 256, 0, stream>>>(col, hist);
    scan_block<<<SCAN_BLOCKS, 1024, 0, stream>>>(hist, hoff, bsum, SCAN_N);
    scan_sums<<<1, 1024, 0, stream>>>(bsum, SCAN_BLOCKS);
    scan_add<<<SCAN_BLOCKS, 1024, 0, stream>>>(hoff, bsum, SCAN_N);
    bin_scatter<<<P1_BLOCKS, 256, 0, stream>>>(row, col, hoff, binned);
    bucket_sort<<<NBKT, 256, 0, stream>>>(binned, hoff, rp, csrc);

    // m0 = relu(x @ mw0 + mb0)   (binned dead from here)
    node_msg0<<<NODE_BLOCKS, 256, 0, stream>>>(x, msg_w, msg_b, mB);

    // L0: h1 = relu([x, agg(m0)] @ ow0 + ob0); m1 = relu(h1 @ mw1 + mb1)
    fused_layer<32, true, false, true><<<NODE_BLOCKS, 256, 0, stream>>>(
        /*x*/ x, /*hin*/ nullptr, /*m*/ mB, rp, csrc,
        /*W1*/ out_w, /*b1*/ out_b, /*W2*/ msg_w + 1024, /*b2*/ msg_b + 32,
        /*hout*/ hA, /*mout*/ mA, /*coords*/ nullptr);

    // L1: h2 = relu([h1, agg(m1)] @ ow1 + ob1) + h1; m2 = relu(h2 @ mw2 + mb2)
    fused_layer<32, false, true, true><<<NODE_BLOCKS, 256, 0, stream>>>(
        /*x*/ nullptr, /*hin*/ hA, /*m*/ mA, rp, csrc,
        /*W1*/ out_w + 2048, /*b1*/ out_b + 32, /*W2*/ msg_w + 2048, /*b2*/ msg_b + 64,
        /*hout*/ hA, /*mout*/ mB, /*coords*/ nullptr);

    // L2: h3 = relu([h2, agg(m2)] @ ow2 + ob2) + h2; m3 = relu(h3 @ mw3 + mb3)
    fused_layer<32, false, true, true><<<NODE_BLOCKS, 256, 0, stream>>>(
        /*x*/ nullptr, /*hin*/ hA, /*m*/ mB, rp, csrc,
        /*W1*/ out_w + 4096, /*b1*/ out_b + 64, /*W2*/ msg_w + 3072, /*b2*/ msg_b + 96,
        /*hout*/ hA, /*mout*/ mA, /*coords*/ nullptr);

    // L3 (final): coords = [h3, agg(m3)] @ last_w + last_b
    fused_layer<2, false, false, false><<<NODE_BLOCKS, 256, 0, stream>>>(
        /*x*/ nullptr, /*hin*/ hA, /*m*/ mA, rp, csrc,
        /*W1*/ last_w, /*b1*/ last_b, /*W2*/ nullptr, /*b2*/ nullptr,
        /*hout*/ nullptr, /*mout*/ nullptr, /*coords*/ coords);
}

// Round 18
// 391.033 us; speedup vs baseline: 1.0445x; 1.0445x over previous
//
#include <hip/hip_runtime.h>
#include <hip/hip_fp16.h>

#define N_NODES 100000
#define N_EDGES 1600000
#define FEAT 32

#define BUCKET_SHIFT 8                       // 256 nodes per bucket
#define NB 391                               // ceil(100000/256)
#define P1_BLOCKS 256
#define EPB (N_EDGES / P1_BLOCKS)            // 6250 edges per pass-1 block
#define EPB2 (EPB / 2)                       // 3125 edge-pairs
#define SCAN_N (NB * P1_BLOCKS)              // 100096
#define STAGE_CAP 6144                       // LDS record cap (24KB)

// ---------------- CSR build: 2-pass LDS-binned counting sort ----------------
// 256 blocks (preserves ~64B per-bucket write runs) x 1024 threads (16 waves/CU
// -> 4x TLP to hide LDS-atomic + load latency; was 4 waves).

__global__ __launch_bounds__(1024) void bin_count(const int* __restrict__ col,
                                                  int* __restrict__ hist) {
    __shared__ int h[NB];
    int t = threadIdx.x;
    for (int i = t; i < NB; i += 1024) h[i] = 0;
    __syncthreads();
    const int2* col2 = (const int2*)(col + blockIdx.x * EPB);
    for (int i = t; i < EPB2; i += 1024) {
        int2 c = col2[i];
        atomicAdd(&h[c.x >> BUCKET_SHIFT], 1);
        atomicAdd(&h[c.y >> BUCKET_SHIFT], 1);
    }
    __syncthreads();
    for (int i = t; i < NB; i += 1024)
        hist[i * P1_BLOCKS + blockIdx.x] = h[i];     // bucket-major
}

__global__ __launch_bounds__(1024) void scan_block(const int* __restrict__ cnt,
                                                   int* __restrict__ ex,
                                                   int* __restrict__ bsum, int n) {
    __shared__ int s[1024];
    int t = threadIdx.x;
    int i = blockIdx.x * 1024 + t;
    int v = (i < n) ? cnt[i] : 0;
    s[t] = v;
    __syncthreads();
    #pragma unroll
    for (int off = 1; off < 1024; off <<= 1) {
        int x = (t >= off) ? s[t - off] : 0;
        __syncthreads();
        s[t] += x;
        __syncthreads();
    }
    if (i < n) ex[i + 1] = s[t];
    if (t == 1023) bsum[blockIdx.x] = s[1023];
}

__global__ __launch_bounds__(128) void scan_sums(int* __restrict__ bsum, int nb) {
    __shared__ int s[128];
    int t = threadIdx.x;
    int v = (t < nb) ? bsum[t] : 0;
    s[t] = v;
    __syncthreads();
    #pragma unroll
    for (int off = 1; off < 128; off <<= 1) {
        int x = (t >= off) ? s[t - off] : 0;
        __syncthreads();
        s[t] += x;
        __syncthreads();
    }
    if (t < nb) bsum[t] = s[t] - v;       // exclusive
}

__global__ __launch_bounds__(1024) void scan_add(int* __restrict__ ex,
                                                 const int* __restrict__ bsum, int n) {
    int i = blockIdx.x * 1024 + threadIdx.x;
    if (i < n) ex[i + 1] += bsum[blockIdx.x];
    if (blockIdx.x == 0 && threadIdx.x == 0) ex[0] = 0;
}

__global__ __launch_bounds__(1024) void bin_scatter(const int* __restrict__ row,
                                                    const int* __restrict__ col,
                                                    const int* __restrict__ hoff,
                                                    int* __restrict__ binned) {
    __shared__ int cur[NB];
    int t = threadIdx.x;
    for (int i = t; i < NB; i += 1024) cur[i] = hoff[i * P1_BLOCKS + blockIdx.x];
    __syncthreads();
    const int2* col2 = (const int2*)(col + blockIdx.x * EPB);
    const int2* row2 = (const int2*)(row + blockIdx.x * EPB);
    for (int i = t; i < EPB2; i += 1024) {
        int2 c = col2[i];
        int2 r = row2[i];
        int p0 = atomicAdd(&cur[c.x >> BUCKET_SHIFT], 1);
        binned[p0] = ((c.x & 255) << 17) | r.x;      // r < 2^17
        int p1 = atomicAdd(&cur[c.y >> BUCKET_SHIFT], 1);
        binned[p1] = ((c.y & 255) << 17) | r.y;
    }
}

// One block per bucket; records staged in LDS (single global read of binned).
__global__ __launch_bounds__(256) void bucket_sort(const int* __restrict__ binned,
                                                   const int* __restrict__ hoff,
                                                   int* __restrict__ rp,
                                                   int* __restrict__ csrc) {
    __shared__ int h[256];
    __shared__ int rec[STAGE_CAP];
    int b = blockIdx.x, t = threadIdx.x;
    int bstart = hoff[b * P1_BLOCKS];
    int bend   = hoff[(b + 1) * P1_BLOCKS];
    int nrec = bend - bstart;
    bool staged = (nrec <= STAGE_CAP);

    h[t] = 0;
    __syncthreads();
    if (staged) {
        for (int i = t; i < nrec; i += 256) {
            int v = binned[bstart + i];
            rec[i] = v;
            atomicAdd(&h[v >> 17], 1);
        }
    } else {
        for (int p = bstart + t; p < bend; p += 256)
            atomicAdd(&h[binned[p] >> 17], 1);
    }
    __syncthreads();
    int deg = h[t];
    #pragma unroll
    for (int off = 1; off < 256; off <<= 1) {       // inclusive scan
        int x = (t >= off) ? h[t - off] : 0;
        __syncthreads();
        h[t] += x;
        __syncthreads();
    }
    int mystart = bstart + h[t] - deg;
    int node = (b << BUCKET_SHIFT) + t;
    if (node < N_NODES) rp[node] = mystart;
    if (b == NB - 1 && t == 0) rp[N_NODES] = N_EDGES;
    __syncthreads();
    h[t] = mystart;                                  // cursor
    __syncthreads();
    if (staged) {
        for (int i = t; i < nrec; i += 256) {
            int v = rec[i];
            int pos = atomicAdd(&h[v >> 17], 1);
            csrc[pos] = v & 0x1FFFF;
        }
    } else {
        for (int p = bstart + t; p < bend; p += 256) {
            int v = binned[p];
            int pos = atomicAdd(&h[v >> 17], 1);
            csrc[pos] = v & 0x1FFFF;
        }
    }
}

// ---------------- layer kernels (R12-proven, fp16 messages) ----------------

// m[n][f] = relu(b[f] + sum_k x[n][k] * W[k][f]) from fp32 x, fp16 out.
__global__ __launch_bounds__(256) void node_msg0(const float* __restrict__ h,
                                                 const float* __restrict__ W,
                                                 const float* __restrict__ b,
                                                 __half* __restrict__ m) {
    __shared__ float WsT[32 * 33];                  // stride 33: conflict-free
    __shared__ float bs[32];
    int t = threadIdx.x;
    for (int i = t; i < 1024; i += 256) {
        int k = i >> 5, f = i & 31;
        WsT[f * 33 + k] = W[i];
    }
    if (t < 32) bs[t] = b[t];
    __syncthreads();

    int node = blockIdx.x * 8 + (t >> 5);           // grid exact: no tail
    int f = t & 31;
    const float4* hp = (const float4*)(h + node * 32);
    const float* wr = &WsT[f * 33];
    float acc = bs[f];
    #pragma unroll
    for (int i = 0; i < 8; i++) {
        float4 q = hp[i];
        acc = fmaf(q.x, wr[4 * i + 0], acc);
        acc = fmaf(q.y, wr[4 * i + 1], acc);
        acc = fmaf(q.z, wr[4 * i + 2], acc);
        acc = fmaf(q.w, wr[4 * i + 3], acc);
    }
    m[node * 32 + f] = __float2half(fmaxf(acc, 0.f));
}

// Fused layer: gather-mean of fp16 m + output matvec -> h_new (+resid), then
// the NEXT layer's message matvec on in-register h_new -> m_out.
// 12 params: x, hin, m, rp, csrc, W1, b1, W2, b2, hout, mout, coords.
template <int OUT, bool XIN, bool RESID, bool MSG>
__global__ __launch_bounds__(256) void fused_layer(
    const float* __restrict__ x,        // 1  fp32 node input (XIN)
    const __half* __restrict__ hin,     // 2  fp16 node input (!XIN); may alias hout
    const __half* __restrict__ m,       // 3  messages of this layer
    const int* __restrict__ rp,         // 4
    const int* __restrict__ csrc,       // 5
    const float* __restrict__ W1,       // 6  [64, OUT] output MLP
    const float* __restrict__ b1,       // 7  [OUT]
    const float* __restrict__ W2,       // 8  [32, 32] next msg MLP (MSG)
    const float* __restrict__ b2,       // 9  [32]
    __half* __restrict__ hout,          // 10 fp16 h_new (OUT==32)
    __half* __restrict__ mout,          // 11 fp16 m_next (MSG)
    float* __restrict__ coords)         // 12 fp32 final out (OUT==2)
{
    __shared__ float Ws1[64 * OUT];
    __shared__ float bs1[OUT];
    __shared__ float Ws2[MSG ? 1024 : 1];
    __shared__ float bs2[MSG ? 32 : 1];
    int t = threadIdx.x;
    for (int i = t; i < 64 * OUT; i += 256) Ws1[i] = W1[i];
    if (t < OUT) bs1[t] = b1[t];
    if (MSG) {
        for (int i = t; i < 1024; i += 256) Ws2[i] = W2[i];
        if (t < 32) bs2[t] = b2[t];
    }
    __syncthreads();

    int node = blockIdx.x * 8 + (t >> 5);           // grid exact: no tail
    int f = t & 31;

    int start = rp[node];
    int end   = rp[node + 1];
    int deg   = end - start;

    float a0 = 0.f, a1 = 0.f, a2 = 0.f, a3 = 0.f;
    int p = start;
    while (p < end) {
        int nrem = end - p;
        int cnt = (nrem < 32) ? nrem : 32;
        int src_f = (f < cnt) ? csrc[p + f] : 0;   // one coalesced load / chunk
        int k = 0;
        for (; k + 4 <= cnt; k += 4) {
            int s0 = __shfl(src_f, k,     32);
            int s1 = __shfl(src_f, k + 1, 32);
            int s2 = __shfl(src_f, k + 2, 32);
            int s3 = __shfl(src_f, k + 3, 32);
            a0 += __half2float(m[s0 * 32 + f]);
            a1 += __half2float(m[s1 * 32 + f]);
            a2 += __half2float(m[s2 * 32 + f]);
            a3 += __half2float(m[s3 * 32 + f]);
        }
        for (; k < cnt; k++) {
            int s = __shfl(src_f, k, 32);
            a0 += __half2float(m[s * 32 + f]);
        }
        p += cnt;
    }
    float agg = (a0 + a1) + (a2 + a3);
    agg = (deg > 0) ? agg / (float)deg : 0.f;

    float hf = XIN ? x[node * 32 + f] : __half2float(hin[node * 32 + f]);

    float acc = (f < OUT) ? bs1[f] : 0.f;
    #pragma unroll
    for (int k = 0; k < 32; k++) {
        float hk = __shfl(hf, k, 32);
        float ak = __shfl(agg, k, 32);
        if (f < OUT) {
            acc = fmaf(hk, Ws1[k * OUT + f], acc);
            acc = fmaf(ak, Ws1[(32 + k) * OUT + f], acc);
        }
    }

    if (OUT == 2) {
        if (f < 2) coords[node * 2 + f] = acc;
        return;
    }

    float hnew = fmaxf(acc, 0.f);
    if (RESID) hnew += hf;
    hout[node * 32 + f] = __float2half(hnew);       // own element only: in-place safe

    if (MSG) {
        float acc2 = bs2[f];
        #pragma unroll
        for (int k = 0; k < 32; k++) {
            float hk = __shfl(hnew, k, 32);
            acc2 = fmaf(hk, Ws2[k * 32 + f], acc2);
        }
        mout[node * 32 + f] = __float2half(fmaxf(acc2, 0.f));
    }
}

// ---------------- launch ----------------

extern "C" void kernel_launch(void* const* d_in, const int* in_sizes, int n_in,
                              void* d_out, int out_size, void* d_ws, size_t ws_size,
                              hipStream_t stream) {
    const float* x      = (const float*)d_in[0];
    const int*   ei     = (const int*)d_in[1];     // [2, E]: row then col
    const float* msg_w  = (const float*)d_in[3];   // [4,32,32]
    const float* msg_b  = (const float*)d_in[4];   // [4,32]
    const float* out_w  = (const float*)d_in[5];   // [3,64,32]
    const float* out_b  = (const float*)d_in[6];   // [3,32]
    const float* last_w = (const float*)d_in[7];   // [64,2]
    const float* last_b = (const float*)d_in[8];   // [2]
    float* coords = (float*)d_out;

    const int* row = ei;
    const int* col = ei + N_EDGES;

    // workspace carve-up (~34 MB); binned overlaps hA (dead before first fused)
    __half* hA = (__half*)d_ws;                     // 6.4 MB
    __half* mA = hA + N_NODES * FEAT;               // 6.4 MB
    __half* mB = mA + N_NODES * FEAT;               // 6.4 MB
    int* rp    = (int*)(mB + N_NODES * FEAT);       // [N+1]
    int* hoff  = rp + (N_NODES + 1);                // [SCAN_N+1]
    int* bsum  = hoff + (SCAN_N + 1);               // [128]
    int* hist  = bsum + 128;                        // [SCAN_N]
    int* csrc  = hist + SCAN_N;                     // [E] 6.4 MB
    int* binned = (int*)hA;                         // [E] 6.4 MB (overlap hA+mA)

    const int SCAN_BLOCKS = (SCAN_N + 1023) / 1024;    // 98
    const int NODE_BLOCKS = N_NODES / 8;               // 12500 exact

    // --- build CSR (by destination), no global atomics ---
    bin_count<<<P1_BLOCKS, 1024, 0, stream>>>(col, hist);
    scan_block<<<SCAN_BLOCKS, 1024, 0, stream>>>(hist, hoff, bsum, SCAN_N);
    scan_sums<<<1, 128, 0, stream>>>(bsum, SCAN_BLOCKS);
    scan_add<<<SCAN_BLOCKS, 1024, 0, stream>>>(hoff, bsum, SCAN_N);
    bin_scatter<<<P1_BLOCKS, 1024, 0, stream>>>(row, col, hoff, binned);
    bucket_sort<<<NB, 256, 0, stream>>>(binned, hoff, rp, csrc);

    // m0 = relu(x @ mw0 + mb0)   (binned dead from here)
    node_msg0<<<NODE_BLOCKS, 256, 0, stream>>>(x, msg_w, msg_b, mB);

    // L0: h1 = relu([x, agg(m0)] @ ow0 + ob0); m1 = relu(h1 @ mw1 + mb1)
    fused_layer<32, true, false, true><<<NODE_BLOCKS, 256, 0, stream>>>(
        /*x*/ x, /*hin*/ nullptr, /*m*/ mB, rp, csrc,
        /*W1*/ out_w, /*b1*/ out_b, /*W2*/ msg_w + 1024, /*b2*/ msg_b + 32,
        /*hout*/ hA, /*mout*/ mA, /*coords*/ nullptr);

    // L1: h2 = relu([h1, agg(m1)] @ ow1 + ob1) + h1; m2 = relu(h2 @ mw2 + mb2)
    fused_layer<32, false, true, true><<<NODE_BLOCKS, 256, 0, stream>>>(
        /*x*/ nullptr, /*hin*/ hA, /*m*/ mA, rp, csrc,
        /*W1*/ out_w + 2048, /*b1*/ out_b + 32, /*W2*/ msg_w + 2048, /*b2*/ msg_b + 64,
        /*hout*/ hA, /*mout*/ mB, /*coords*/ nullptr);

    // L2: h3 = relu([h2, agg(m2)] @ ow2 + ob2) + h2; m3 = relu(h3 @ mw3 + mb3)
    fused_layer<32, false, true, true><<<NODE_BLOCKS, 256, 0, stream>>>(
        /*x*/ nullptr, /*hin*/ hA, /*m*/ mB, rp, csrc,
        /*W1*/ out_w + 4096, /*b1*/ out_b + 64, /*W2*/ msg_w + 3072, /*b2*/ msg_b + 96,
        /*hout*/ hA, /*mout*/ mA, /*coords*/ nullptr);

    // L3 (final): coords = [h3, agg(m3)] @ last_w + last_b
    fused_layer<2, false, false, false><<<NODE_BLOCKS, 256, 0, stream>>>(
        /*x*/ nullptr, /*hin*/ hA, /*m*/ mA, rp, csrc,
        /*W1*/ last_w, /*b1*/ last_b, /*W2*/ nullptr, /*b2*/ nullptr,
        /*hout*/ nullptr, /*mout*/ nullptr, /*coords*/ coords);
}